// Round 3
// baseline (230.937 us; speedup 1.0000x reference)
//
#include <hip/hip_runtime.h>
#include <hip/hip_bf16.h>

// Longformer self-attention, MI355X gfx950 — ROUND 15.
// fp32 I/O, f16 intermediates. Changes vs R14:
//  (1) qkv_mfma7: STRUCTURAL rewrite to the 256^2 8-wave template (guide §5,
//      m198/m201 evidence): BM=BN=256, BK=32, 512 thr, wave grid 2x4, each
//      wave 128x64 out (acc[8][4]). 4 LDS K-tile buffers (A+B 32KB each,
//      128KB), prefetch depth 3: per K-tile ONE raw s_barrier + ONE counted
//      s_waitcnt vmcnt(8) (loads for t+1/t+2 stay in flight across the
//      barrier; drain only in last 2 tiles). Two 16-MFMA phases per tile
//      with s_setprio(1/0) (T5 pays only in role-split schedules).
//      12 ds_read_b128 / 32 MFMA per wave-tile; R13-verified XOR swizzle.
//      Reads per block 2x reused vs 128^2 (382 MB vs 760 MB L2-level).
//      R12-R14 proved the 128^2/4-wave structure flat at ~88us regardless
//      of schedule; this changes the structure, not just the schedule.
//  (2) epilogue: Cl = 256x264 f16 (135KB) unions into staging LDS.
// prep / band_mfma5 / global_part / global_reduce unchanged (proven).

#define DEVI __device__ __forceinline__
typedef _Float16 f16;
typedef _Float16 h4 __attribute__((ext_vector_type(4)));
typedef _Float16 f16x8 __attribute__((ext_vector_type(8)));
typedef __attribute__((ext_vector_type(4))) float float4v;

DEVI float4v mfma16(f16x8 a, f16x8 b, float4v c) {
    return __builtin_amdgcn_mfma_f32_16x16x32_f16(a, b, c, 0, 0, 0);
}

DEVI void gl_lds16(const f16* g, f16* l) {
    __builtin_amdgcn_global_load_lds(
        (const __attribute__((address_space(1))) unsigned int*)g,
        (__attribute__((address_space(3))) unsigned int*)l, 16, 0, 0);
}

// ---------------------------------------------------------------------------
// prep: blocks [0,6144) = xcast (fp32->f16, 8192*768); blocks [6144,7008) =
// weight transpose Wt[i*768+n][k] = (f16) W_i[k][n].
// ---------------------------------------------------------------------------
__global__ __launch_bounds__(256) void prep(
    const float* __restrict__ x,
    const float* __restrict__ w0, const float* __restrict__ w1,
    const float* __restrict__ w2, const float* __restrict__ w3,
    const float* __restrict__ w4, const float* __restrict__ w5,
    f16* __restrict__ xh, f16* __restrict__ wt) {
    __shared__ float tile[64][65];
    int bid = blockIdx.x;
    if (bid < 6144) {
        int i = (bid * 256 + threadIdx.x) * 4;
        float4 v = *(const float4*)&x[i];
        h4 o = {(f16)v.x, (f16)v.y, (f16)v.z, (f16)v.w};
        *(h4*)&xh[i] = o;
    } else {
        int t = bid - 6144;
        int i = t / 144, rem = t - i * 144;
        int n0 = (rem % 12) * 64, k0 = (rem / 12) * 64;
        const float* W = (i == 0) ? w0 : (i == 1) ? w1 : (i == 2) ? w2
                       : (i == 3) ? w3 : (i == 4) ? w4 : w5;
        int tx = threadIdx.x & 63, ty = threadIdx.x >> 6;
#pragma unroll
        for (int yy = 0; yy < 64; yy += 4)
            tile[yy + ty][tx] = W[(size_t)(k0 + yy + ty) * 768 + n0 + tx];
        __syncthreads();
#pragma unroll
        for (int yy = 0; yy < 64; yy += 4)
            wt[(size_t)(i * 768 + n0 + yy + ty) * 768 + k0 + tx] = (f16)tile[tx][yy + ty];
    }
}

// ---------------------------------------------------------------------------
// qkv_mfma7: 256x256 tile, 8 waves, 4-deep K-tile ring, counted vmcnt.
// ---------------------------------------------------------------------------
__global__ __launch_bounds__(512, 2) void qkv_mfma7(
    const f16* __restrict__ Xh, const f16* __restrict__ Wt,
    const float* __restrict__ b0, const float* __restrict__ b1,
    const float* __restrict__ b2, const float* __restrict__ b3,
    const float* __restrict__ b4, const float* __restrict__ b5,
    f16* __restrict__ q, f16* __restrict__ k, f16* __restrict__ vT,
    f16* __restrict__ qg, f16* __restrict__ kg, f16* __restrict__ vgT) {
    constexpr int CLD = 264;
    __shared__ __align__(16) char smem[256 * CLD * 2];   // 135168 B; staging unions
    f16* As = (f16*)smem;                                // 4 bufs x 8192 f16 (16KB)
    f16* Bs = (f16*)(smem + 65536);                      // 4 bufs x 8192 f16
    f16* Cl = (f16*)smem;                                // aliased epilogue buf

    int tid = threadIdx.x, lane = tid & 63, wid = tid >> 6;
    int quad = lane >> 4, l15 = lane & 15;
    int wr = wid >> 2, wc = wid & 3;                     // wave grid 2(M) x 4(N)
    int m0 = blockIdx.x * 256;
    int grp = blockIdx.y / 3;
    if (grp == 3 && (m0 & 4095) != 0) return;            // qg: only s<32 tiles matter
    int nb = (blockIdx.y - grp * 3) * 256;
    const f16* arow0 = Xh + (size_t)m0 * 768;
    const f16* brow0 = Wt + (size_t)(grp * 768 + nb) * 768;

    // staging geometry (verified R13 swizzle): thread stages one 16B chunk per
    // half; row rS = tid>>2 (of 128), lds chunk tid&3 holds global chunk
    // (tid&3)^((rS>>1)&3). Read side: chunk quad^((l15>>1)&3).
    int rS = tid >> 2;
    int cgS = (((tid & 3) ^ ((rS >> 1) & 3)) << 3);
    int sw8 = ((quad ^ ((l15 >> 1) & 3)) << 3);
    f16* Asw = As + wid * 512;                           // wave-uniform LDS bases
    f16* Bsw = Bs + wid * 512;
    int wrb = wr * 128;                                  // wave A-row base
    int wcb = wc * 64;                                   // wave B-row base

    float4v acc[8][4];
#pragma unroll
    for (int mt = 0; mt < 8; ++mt)
#pragma unroll
        for (int nt = 0; nt < 4; ++nt) acc[mt][nt] = (float4v){0.f, 0.f, 0.f, 0.f};

    // stage all 4 halves (A h0,h1 + B h0,h1) of one K-tile: 4 loads/thread
#define STAGE_T(K0, SBUF)                                                      \
    do {                                                                       \
        gl_lds16(&arow0[(size_t)rS * 768 + (K0) + cgS], Asw + (SBUF) * 8192);  \
        gl_lds16(&arow0[(size_t)(128 + rS) * 768 + (K0) + cgS],                \
                 Asw + (SBUF) * 8192 + 4096);                                  \
        gl_lds16(&brow0[(size_t)rS * 768 + (K0) + cgS], Bsw + (SBUF) * 8192);  \
        gl_lds16(&brow0[(size_t)(128 + rS) * 768 + (K0) + cgS],                \
                 Bsw + (SBUF) * 8192 + 4096);                                  \
    } while (0)

    // One K-tile: counted vmcnt -> barrier -> stage(t+3) -> 2 MFMA phases.
    // Safety: staged buffer (t+3)&3 == (t-1)&3, fully consumed before this
    // tile's barrier (each wave's ds_reads retire at lgkmcnt before its
    // MFMAs, which precede the barrier). vmcnt(8) leaves tiles t+1,t+2
    // (4 loads each) in flight.
#define TILE(K3, BUF, SBUF, WN, DOSTG)                                         \
    do {                                                                       \
        asm volatile("s_waitcnt vmcnt(" #WN ")" ::: "memory");                 \
        __builtin_amdgcn_s_barrier();                                          \
        __builtin_amdgcn_sched_barrier(0);                                     \
        const f16* Ab = As + (BUF) * 8192;                                     \
        const f16* Bb = Bs + (BUF) * 8192;                                     \
        if (DOSTG) {                                                           \
            gl_lds16(&arow0[(size_t)rS * 768 + (K3) + cgS],                    \
                     Asw + (SBUF) * 8192);                                     \
            gl_lds16(&arow0[(size_t)(128 + rS) * 768 + (K3) + cgS],            \
                     Asw + (SBUF) * 8192 + 4096);                              \
        }                                                                      \
        f16x8 bfv[4];                                                          \
        _Pragma("unroll") for (int j = 0; j < 4; ++j)                          \
            bfv[j] = *(const f16x8*)&Bb[(wcb + j * 16 + l15) * 32 + sw8];      \
        {                                                                      \
            f16x8 af[4];                                                       \
            _Pragma("unroll") for (int i = 0; i < 4; ++i)                      \
                af[i] = *(const f16x8*)&Ab[(wrb + i * 16 + l15) * 32 + sw8];   \
            __builtin_amdgcn_s_setprio(1);                                     \
            _Pragma("unroll") for (int i = 0; i < 4; ++i)                      \
                _Pragma("unroll") for (int j = 0; j < 4; ++j)                  \
                    acc[i][j] = mfma16(af[i], bfv[j], acc[i][j]);              \
            __builtin_amdgcn_s_setprio(0);                                     \
        }                                                                      \
        if (DOSTG) {                                                           \
            gl_lds16(&brow0[(size_t)rS * 768 + (K3) + cgS],                    \
                     Bsw + (SBUF) * 8192);                                     \
            gl_lds16(&brow0[(size_t)(128 + rS) * 768 + (K3) + cgS],            \
                     Bsw + (SBUF) * 8192 + 4096);                              \
        }                                                                      \
        {                                                                      \
            f16x8 af[4];                                                       \
            _Pragma("unroll") for (int i = 0; i < 4; ++i)                      \
                af[i] = *(const f16x8*)&Ab[(wrb + 64 + i * 16 + l15) * 32 + sw8]; \
            __builtin_amdgcn_s_setprio(1);                                     \
            _Pragma("unroll") for (int i = 0; i < 4; ++i)                      \
                _Pragma("unroll") for (int j = 0; j < 4; ++j)                  \
                    acc[4 + i][j] = mfma16(af[i], bfv[j], acc[4 + i][j]);      \
            __builtin_amdgcn_s_setprio(0);                                     \
        }                                                                      \
    } while (0)

    STAGE_T(0, 0);
    STAGE_T(32, 1);
    STAGE_T(64, 2);
    for (int m = 0; m < 5; ++m) {                        // tiles t = 4m..4m+3 (0..19)
        int kb = m * 128;
        TILE(kb + 96, 0, 3, 8, true);                    // t=4m   stages t+3
        TILE(kb + 128, 1, 0, 8, true);
        TILE(kb + 160, 2, 1, 8, true);
        TILE(kb + 192, 3, 2, 8, true);
    }
    TILE(736, 0, 3, 8, true);                            // t=20 stages t=23
    TILE(0, 1, 0, 8, false);                             // t=21
    TILE(0, 2, 0, 4, false);                             // t=22
    TILE(0, 3, 0, 0, false);                             // t=23
#undef TILE
#undef STAGE_T

    __syncthreads();   // full drain; A/B region now reusable as Cl

    const float* Bsel = (grp == 0) ? b0 : (grp == 1) ? b1 : (grp == 2) ? b2
                      : (grp == 3) ? b3 : (grp == 4) ? b4 : b5;
    int b = m0 >> 12;
    bool tr = (grp == 2 || grp == 5);

    if (tr) {
#pragma unroll
        for (int nt = 0; nt < 4; ++nt) {
            float bias = Bsel[nb + wcb + nt * 16 + l15];
#pragma unroll
            for (int mt = 0; mt < 8; ++mt) {
                float4v a = acc[mt][nt];
                h4 pk = {(f16)(a[0] + bias), (f16)(a[1] + bias),
                         (f16)(a[2] + bias), (f16)(a[3] + bias)};
                *(h4*)&Cl[(wcb + nt * 16 + l15) * CLD + wrb + mt * 16 + quad * 4] = pk;
            }
        }
    } else {
        float scale = (grp == 0 || grp == 3) ? 0.125f : 1.0f;
#pragma unroll
        for (int nt = 0; nt < 4; ++nt) {
            float bias = Bsel[nb + wcb + nt * 16 + l15];
#pragma unroll
            for (int mt = 0; mt < 8; ++mt) {
                float4v a = acc[mt][nt];
#pragma unroll
                for (int r = 0; r < 4; ++r)
                    Cl[(wrb + mt * 16 + quad * 4 + r) * CLD + wcb + nt * 16 + l15] =
                        (f16)((a[r] + bias) * scale);
            }
        }
    }
    __syncthreads();

    if (tr) {
        f16* base = (grp == 2) ? vT : vgT;
        int nn = tid >> 1, hf = tid & 1;
        int ncol = nb + nn, h = ncol >> 6, hd = ncol & 63;
        const f16* src = &Cl[nn * CLD + hf * 128];
        f16* dst = &base[((size_t)((b * 12 + h) * 64 + hd)) * 4096 + (m0 & 4095) + hf * 128];
#pragma unroll
        for (int i = 0; i < 16; ++i)
            *(f16x8*)&dst[i * 8] = *(const f16x8*)&src[i * 8];
    } else {
        int rr = tid >> 1, hf = tid & 1;
        int s = (m0 & 4095) + rr;
        const f16* src = &Cl[rr * CLD + hf * 128];
        int hb = nb >> 6;
        if (grp == 3) {
            if (s < 32) {
#pragma unroll
                for (int i = 0; i < 16; ++i) {
                    int h = hb + hf * 2 + (i >> 3), hd = (i & 7) * 8;
                    *(f16x8*)&qg[((size_t)((b * 12 + h) * 32 + s)) * 64 + hd] =
                        *(const f16x8*)&src[i * 8];
                }
            }
        } else {
            f16* baseb = (grp == 0) ? q : (grp == 1) ? k : kg;
#pragma unroll
            for (int i = 0; i < 16; ++i) {
                int h = hb + hf * 2 + (i >> 3), hd = (i & 7) * 8;
                *(f16x8*)&baseb[((size_t)((b * 12 + h) * 4096 + s)) * 64 + hd] =
                    *(const f16x8*)&src[i * 8];
            }
        }
    }
}

// ---------------------------------------------------------------------------
// band_mfma5 — unchanged from R11 (proven).
// ---------------------------------------------------------------------------
__global__ __launch_bounds__(256, 3) void band_mfma5(
    const f16* __restrict__ q, const f16* __restrict__ k, const f16* __restrict__ vT,
    float* __restrict__ out) {
    constexpr int LDK = 72, LDV = 136, LDP = 40;
    __shared__ __align__(16) f16 Kt[128 * LDK];
    __shared__ __align__(16) f16 Vt[64 * LDV];
    __shared__ __align__(16) f16 Pt[4][32 * LDP];
    int tid = threadIdx.x, lane = tid & 63, wid = tid >> 6;
    int quad = lane >> 4, l15 = lane & 15;
    int c = blockIdx.x & 31, h = (blockIdx.x >> 5) % 12, b = blockIdx.x / 384;
    const f16* qsl = q + (size_t)(b * 12 + h) * 4096 * 64;
    const f16* ksl = k + (size_t)(b * 12 + h) * 4096 * 64;
    const f16* vsl = vT + (size_t)(b * 12 + h) * 64 * 4096;
    int q0 = c * 128;
    int pq0 = q0 + wid * 32;

    f16x8 qf[2][2];
#pragma unroll
    for (int qg = 0; qg < 2; ++qg)
#pragma unroll
        for (int ks = 0; ks < 2; ++ks)
            qf[qg][ks] = *(const f16x8*)&qsl[(size_t)(pq0 + qg * 16 + l15) * 64 +
                                             ks * 32 + quad * 8];

    float4v Ot[4][2];
#pragma unroll
    for (int dt = 0; dt < 4; ++dt)
#pragma unroll
        for (int qg = 0; qg < 2; ++qg) Ot[dt][qg] = (float4v){0.f, 0.f, 0.f, 0.f};
    float lacc[2] = {0.f, 0.f};
    f16* PW = &Pt[wid][0];

    {
#pragma unroll
        for (int jt = 0; jt < 2; ++jt) {
            f16x8 kf0 = *(const f16x8*)&ksl[(size_t)(jt * 16 + l15) * 64 + quad * 8];
            f16x8 kf1 = *(const f16x8*)&ksl[(size_t)(jt * 16 + l15) * 64 + 32 + quad * 8];
#pragma unroll
            for (int qg = 0; qg < 2; ++qg) {
                float4v sacc = (float4v){0.f, 0.f, 0.f, 0.f};
                sacc = mfma16(kf0, qf[qg][0], sacc);
                sacc = mfma16(kf1, qf[qg][1], sacc);
                float p0 = __expf(sacc[0]), p1 = __expf(sacc[1]);
                float p2 = __expf(sacc[2]), p3 = __expf(sacc[3]);
                lacc[qg] += (p0 + p1) + (p2 + p3);
                h4 pk = {(f16)p0, (f16)p1, (f16)p2, (f16)p3};
                *(h4*)&PW[(qg * 16 + l15) * LDP + jt * 16 + quad * 4] = pk;
            }
        }
        f16x8 pf0 = *(const f16x8*)&PW[l15 * LDP + quad * 8];
        f16x8 pf1 = *(const f16x8*)&PW[(16 + l15) * LDP + quad * 8];
#pragma unroll
        for (int dt = 0; dt < 4; ++dt) {
            f16x8 vf = *(const f16x8*)&vsl[(size_t)(dt * 16 + l15) * 4096 + quad * 8];
            Ot[dt][0] = mfma16(vf, pf0, Ot[dt][0]);
            Ot[dt][1] = mfma16(vf, pf1, Ot[dt][1]);
        }
    }

    for (int r = 0; r < 5; ++r) {
        int kb = q0 - 256 + r * 128;
        if (kb < 0 || kb >= 4096) continue;
        __syncthreads();
        {
            int kr = tid >> 1, ko = (tid & 1) * 32;
            const f16* ks2 = &ksl[(size_t)(kb + kr) * 64 + ko];
            f16* kd = &Kt[kr * LDK + ko];
#pragma unroll
            for (int i = 0; i < 4; ++i) *(f16x8*)&kd[i * 8] = *(const f16x8*)&ks2[i * 8];
            int vr = tid >> 2, vo = (tid & 3) * 32;
            const f16* vs2 = &vsl[(size_t)vr * 4096 + kb + vo];
            f16* vd = &Vt[vr * LDV + vo];
#pragma unroll
            for (int i = 0; i < 4; ++i) *(f16x8*)&vd[i * 8] = *(const f16x8*)&vs2[i * 8];
        }
        __syncthreads();

        if (kb + 127 < pq0 - 256 || kb > pq0 + 287) continue;

#pragma unroll
        for (int tt = 0; tt < 2; ++tt) {
            int tb = kb + tt * 64;
            if (tb + 63 < pq0 - 256 || tb > pq0 + 287) continue;
#pragma unroll
            for (int hf = 0; hf < 2; ++hf) {
#pragma unroll
                for (int jt = 0; jt < 2; ++jt) {
                    int jl = tt * 64 + hf * 32 + jt * 16;
                    f16x8 kf0 = *(const f16x8*)&Kt[(jl + l15) * LDK + quad * 8];
                    f16x8 kf1 = *(const f16x8*)&Kt[(jl + l15) * LDK + 32 + quad * 8];
                    int j0 = kb + jl;
#pragma unroll
                    for (int qg = 0; qg < 2; ++qg) {
                        int qlo = pq0 + qg * 16;
                        h4 pk = {(f16)0.f, (f16)0.f, (f16)0.f, (f16)0.f};
                        bool dead = (j0 < qlo - 271) || (j0 > qlo + 271);
                        if (!dead) {
                            float4v sacc = (float4v){0.f, 0.f, 0.f, 0.f};
                            sacc = mfma16(kf0, qf[qg][0], sacc);
                            sacc = mfma16(kf1, qf[qg][1], sacc);
                            float p[4];
                            bool full = (j0 >= qlo - 241) && (j0 <= qlo + 241);
                            if (full) {
#pragma unroll
                                for (int rr = 0; rr < 4; ++rr) p[rr] = __expf(sacc[rr]);
                            } else {
#pragma unroll
                                for (int rr = 0; rr < 4; ++rr) {
                                    int d = (j0 + quad * 4 + rr) - (qlo + l15);
                                    p[rr] = ((unsigned)(d + 256) <= 512u) ? __expf(sacc[rr]) : 0.f;
                                }
                            }
                            lacc[qg] += (p[0] + p[1]) + (p[2] + p[3]);
                            pk = (h4){(f16)p[0], (f16)p[1], (f16)p[2], (f16)p[3]};
                        }
                        *(h4*)&PW[(qg * 16 + l15) * LDP + jt * 16 + quad * 4] = pk;
                    }
                }
                f16x8 pf0 = *(const f16x8*)&PW[l15 * LDP + quad * 8];
                f16x8 pf1 = *(const f16x8*)&PW[(16 + l15) * LDP + quad * 8];
#pragma unroll
                for (int dt = 0; dt < 4; ++dt) {
                    f16x8 vf = *(const f16x8*)&Vt[(dt * 16 + l15) * LDV +
                                                  tt * 64 + hf * 32 + quad * 8];
                    Ot[dt][0] = mfma16(vf, pf0, Ot[dt][0]);
                    Ot[dt][1] = mfma16(vf, pf1, Ot[dt][1]);
                }
            }
        }
    }

#pragma unroll
    for (int qg = 0; qg < 2; ++qg) {
        float lsum = lacc[qg];
        lsum += __shfl_xor(lsum, 16);
        lsum += __shfl_xor(lsum, 32);
        float inv = 1.f / lsum;
        size_t orow = (size_t)(b * 4096 + pq0 + qg * 16 + l15) * 768 + h * 64;
#pragma unroll
        for (int dt = 0; dt < 4; ++dt) {
            float4 o4 = {Ot[dt][qg][0] * inv, Ot[dt][qg][1] * inv,
                         Ot[dt][qg][2] * inv, Ot[dt][qg][3] * inv};
            *(float4*)&out[orow + dt * 16 + quad * 4] = o4;
        }
    }
}

// ---------------------------------------------------------------------------
// global_part / global_reduce — unchanged from R11 (proven).
// ---------------------------------------------------------------------------
__global__ __launch_bounds__(256) void global_part(
    const f16* __restrict__ qg, const f16* __restrict__ kg, const f16* __restrict__ vgT,
    float* __restrict__ Opart, float* __restrict__ Lpart) {
    constexpr int LDP = 72;
    __shared__ __align__(16) f16 Pt[4][32 * LDP];
    __shared__ __align__(16) float Osh[4][64 * 32];
    __shared__ float Lsh[4][32];
    int tid = threadIdx.x, lane = tid & 63, wid = tid >> 6;
    int quad = lane >> 4, l15 = lane & 15;
    int sl = blockIdx.x & 7, bh = blockIdx.x >> 3;
    const f16* qsl = qg + (size_t)bh * 32 * 64;
    const f16* ksl = kg + (size_t)bh * 4096 * 64;
    const f16* vsl = vgT + (size_t)bh * 64 * 4096;
    int kbase = sl * 512 + wid * 128;

    f16x8 qf[2][2];
#pragma unroll
    for (int g = 0; g < 2; ++g)
#pragma unroll
        for (int ks = 0; ks < 2; ++ks)
            qf[g][ks] = *(const f16x8*)&qsl[(size_t)(g * 16 + l15) * 64 + ks * 32 + quad * 8];

    float4v Ot[4][2];
#pragma unroll
    for (int dt = 0; dt < 4; ++dt)
#pragma unroll
        for (int g = 0; g < 2; ++g) Ot[dt][g] = (float4v){0.f, 0.f, 0.f, 0.f};
    float lacc[2] = {0.f, 0.f};
    f16* PW = &Pt[wid][0];

#pragma unroll
    for (int hf = 0; hf < 2; ++hf) {
        int kh0 = kbase + hf * 64;
#pragma unroll
        for (int kt = 0; kt < 4; ++kt) {
            int jb = kh0 + kt * 16;
            f16x8 kf0 = *(const f16x8*)&ksl[(size_t)(jb + l15) * 64 + quad * 8];
            f16x8 kf1 = *(const f16x8*)&ksl[(size_t)(jb + l15) * 64 + 32 + quad * 8];
#pragma unroll
            for (int g = 0; g < 2; ++g) {
                float4v sacc = (float4v){0.f, 0.f, 0.f, 0.f};
                sacc = mfma16(kf0, qf[g][0], sacc);
                sacc = mfma16(kf1, qf[g][1], sacc);
                float p0 = __expf(sacc[0]), p1 = __expf(sacc[1]);
                float p2 = __expf(sacc[2]), p3 = __expf(sacc[3]);
                lacc[g] += (p0 + p1) + (p2 + p3);
                h4 pk = {(f16)p0, (f16)p1, (f16)p2, (f16)p3};
                *(h4*)&PW[(g * 16 + l15) * LDP + kt * 16 + quad * 4] = pk;
            }
        }
#pragma unroll
        for (int kh = 0; kh < 2; ++kh) {
            f16x8 pf0 = *(const f16x8*)&PW[l15 * LDP + kh * 32 + quad * 8];
            f16x8 pf1 = *(const f16x8*)&PW[(16 + l15) * LDP + kh * 32 + quad * 8];
#pragma unroll
            for (int dt = 0; dt < 4; ++dt) {
                f16x8 vf = *(const f16x8*)&vsl[(size_t)(dt * 16 + l15) * 4096 +
                                               kh0 + kh * 32 + quad * 8];
                Ot[dt][0] = mfma16(vf, pf0, Ot[dt][0]);
                Ot[dt][1] = mfma16(vf, pf1, Ot[dt][1]);
            }
        }
    }

#pragma unroll
    for (int g = 0; g < 2; ++g) {
        lacc[g] += __shfl_xor(lacc[g], 16);
        lacc[g] += __shfl_xor(lacc[g], 32);
    }
    if (quad == 0) { Lsh[wid][l15] = lacc[0]; Lsh[wid][16 + l15] = lacc[1]; }
#pragma unroll
    for (int dt = 0; dt < 4; ++dt)
#pragma unroll
        for (int g = 0; g < 2; ++g)
#pragma unroll
            for (int r = 0; r < 4; ++r)
                Osh[wid][(dt * 16 + quad * 4 + r) * 32 + g * 16 + l15] = Ot[dt][g][r];
    __syncthreads();
#pragma unroll
    for (int i = 0; i < 8; ++i) {
        int idx = tid + i * 256;
        int d = idx & 63, qq = idx >> 6;
        float v = Osh[0][d * 32 + qq] + Osh[1][d * 32 + qq] +
                  Osh[2][d * 32 + qq] + Osh[3][d * 32 + qq];
        Opart[(size_t)blockIdx.x * 2048 + idx] = v;
    }
    if (tid < 32)
        Lpart[blockIdx.x * 32 + tid] = Lsh[0][tid] + Lsh[1][tid] + Lsh[2][tid] + Lsh[3][tid];
}

__global__ __launch_bounds__(256) void global_reduce(
    const float* __restrict__ Opart, const float* __restrict__ Lpart,
    float* __restrict__ out) {
    __shared__ float Ls[32];
    int tid = threadIdx.x, bh = blockIdx.x;
    int b = bh / 12, h = bh % 12;
    if (tid < 32) {
        float s = 0.f;
#pragma unroll
        for (int sl = 0; sl < 8; ++sl) s += Lpart[(bh * 8 + sl) * 32 + tid];
        Ls[tid] = s;
    }
    __syncthreads();
#pragma unroll
    for (int i = 0; i < 8; ++i) {
        int idx = tid + i * 256;
        int d = idx & 63, qq = idx >> 6;
        float o = 0.f;
#pragma unroll
        for (int sl = 0; sl < 8; ++sl) o += Opart[(size_t)(bh * 8 + sl) * 2048 + idx];
        out[(size_t)(b * 4096 + qq) * 768 + h * 64 + d] = o / Ls[qq];
    }
}

// ---------------------------------------------------------------------------
extern "C" void kernel_launch(void* const* d_in, const int* in_sizes, int n_in,
                              void* d_out, int out_size, void* d_ws, size_t ws_size,
                              hipStream_t stream) {
    const float* hs = (const float*)d_in[0];
    float* outp = (float*)d_out;

    char* p = (char*)d_ws;
    const size_t SLAB = (size_t)2 * 12 * 4096 * 64 * sizeof(f16);   // 12,582,912 B
    f16* qb   = (f16*)(p + 0 * SLAB);
    f16* kb   = (f16*)(p + 1 * SLAB);
    f16* vtb  = (f16*)(p + 2 * SLAB);   // [bh][d][s]
    f16* kgb  = (f16*)(p + 3 * SLAB);
    f16* vgtb = (f16*)(p + 4 * SLAB);   // [bh][d][s]
    f16* qgb  = (f16*)(p + 5 * SLAB);
    char* p2  = p + 5 * SLAB + 196608;
    f16* xh   = (f16*)p2;
    f16* wt   = (f16*)(p2 + SLAB);
    char* p3  = p2 + SLAB + 7077888;
    float* Opart = (float*)p3;
    float* Lpart = (float*)(p3 + 1572864);

    prep<<<7008, 256, 0, stream>>>(
        hs,
        (const float*)d_in[1], (const float*)d_in[3], (const float*)d_in[5],
        (const float*)d_in[7], (const float*)d_in[9], (const float*)d_in[11],
        xh, wt);
    qkv_mfma7<<<dim3(32, 18), 512, 0, stream>>>(
        xh, wt,
        (const float*)d_in[2], (const float*)d_in[4], (const float*)d_in[6],
        (const float*)d_in[8], (const float*)d_in[10], (const float*)d_in[12],
        qb, kb, vtb, qgb, kgb, vgtb);
    band_mfma5<<<768, 256, 0, stream>>>(qb, kb, vtb, outp);
    global_part<<<192, 256, 0, stream>>>(qgb, kgb, vgtb, Opart, Lpart);
    global_reduce<<<24, 256, 0, stream>>>(Opart, Lpart, outp);
}

// Round 4
// 225.035 us; speedup vs baseline: 1.0262x; 1.0262x over previous
//
#include <hip/hip_runtime.h>
#include <hip/hip_bf16.h>

// Longformer self-attention, MI355X gfx950 — ROUND 16.
// fp32 I/O, f16 intermediates. Changes vs R15: revert to R14's proven 128^2
// 4-wave ring skeleton (2 blocks/CU), then attack the DIAGNOSED wall:
//  (1) XCD-aware block remap: linear id L -> xcd=L&7, W=L>>3; m_tile =
//      xcd*8 + (W&7), y = W>>3. Each XCD owns an 8-m-tile Xh slice
//      (1.57 MB, fits its private 4MB L2; default x-major order thrashed
//      12.6MB Xh across XCDs -> FETCH 45MB vs 20MB compulsory, A-loads at
//      HBM latency ~900cy -> depth-3 pipeline equilibrium ~585cy/tile =
//      the flat 88us of R12-R15). Concurrent same-y blocks in an XCD also
//      share the Wt n-tile (~0.8MB streaming window). Both load classes
//      become mostly-L2-hit (~200cy), which depth-3/5 prefetch CAN hide.
//  (2) B-ring deepened to 6 (A ring 4): B-stage lead 5 tiles. LDS 80KB =
//      4x8KB A + 6x8KB B; Cl epilogue unions in; still 2 blocks/CU.
//      vmcnt re-audited: steady N=10 (A(t) has 10 newer loads, B(t) 16);
//      tail N = 10,8,6,2,0. Prologue: A0..A2 then B0..B4, first wait N=8.
//  (3) s_setprio(1/0) around the 16-MFMA cluster.
// prep / band_mfma5 / global_part / global_reduce unchanged (proven).

#define DEVI __device__ __forceinline__
typedef _Float16 f16;
typedef _Float16 h4 __attribute__((ext_vector_type(4)));
typedef _Float16 f16x8 __attribute__((ext_vector_type(8)));
typedef __attribute__((ext_vector_type(4))) float float4v;

DEVI float4v mfma16(f16x8 a, f16x8 b, float4v c) {
    return __builtin_amdgcn_mfma_f32_16x16x32_f16(a, b, c, 0, 0, 0);
}

DEVI void gl_lds16(const f16* g, f16* l) {
    __builtin_amdgcn_global_load_lds(
        (const __attribute__((address_space(1))) unsigned int*)g,
        (__attribute__((address_space(3))) unsigned int*)l, 16, 0, 0);
}

// ---------------------------------------------------------------------------
// prep: blocks [0,6144) = xcast (fp32->f16, 8192*768); blocks [6144,7008) =
// weight transpose Wt[i*768+n][k] = (f16) W_i[k][n].
// ---------------------------------------------------------------------------
__global__ __launch_bounds__(256) void prep(
    const float* __restrict__ x,
    const float* __restrict__ w0, const float* __restrict__ w1,
    const float* __restrict__ w2, const float* __restrict__ w3,
    const float* __restrict__ w4, const float* __restrict__ w5,
    f16* __restrict__ xh, f16* __restrict__ wt) {
    __shared__ float tile[64][65];
    int bid = blockIdx.x;
    if (bid < 6144) {
        int i = (bid * 256 + threadIdx.x) * 4;
        float4 v = *(const float4*)&x[i];
        h4 o = {(f16)v.x, (f16)v.y, (f16)v.z, (f16)v.w};
        *(h4*)&xh[i] = o;
    } else {
        int t = bid - 6144;
        int i = t / 144, rem = t - i * 144;
        int n0 = (rem % 12) * 64, k0 = (rem / 12) * 64;
        const float* W = (i == 0) ? w0 : (i == 1) ? w1 : (i == 2) ? w2
                       : (i == 3) ? w3 : (i == 4) ? w4 : w5;
        int tx = threadIdx.x & 63, ty = threadIdx.x >> 6;
#pragma unroll
        for (int yy = 0; yy < 64; yy += 4)
            tile[yy + ty][tx] = W[(size_t)(k0 + yy + ty) * 768 + n0 + tx];
        __syncthreads();
#pragma unroll
        for (int yy = 0; yy < 64; yy += 4)
            wt[(size_t)(i * 768 + n0 + yy + ty) * 768 + k0 + tx] = (f16)tile[tx][yy + ty];
    }
}

// ---------------------------------------------------------------------------
// qkv_mfma8: R14 ring skeleton + XCD remap + B-ring-6 + setprio.
// ---------------------------------------------------------------------------
__global__ __launch_bounds__(256) void qkv_mfma8(
    const f16* __restrict__ Xh, const f16* __restrict__ Wt,
    const float* __restrict__ b0, const float* __restrict__ b1,
    const float* __restrict__ b2, const float* __restrict__ b3,
    const float* __restrict__ b4, const float* __restrict__ b5,
    f16* __restrict__ q, f16* __restrict__ k, f16* __restrict__ vT,
    f16* __restrict__ qg, f16* __restrict__ kg, f16* __restrict__ vgT) {
    constexpr int CLD = 136;
    __shared__ __align__(16) char smem[81920];           // 32KB A-ring + 48KB B-ring
    f16* As = (f16*)smem;                                // 4 bufs x 4096 f16 (8KB)
    f16* Bs = (f16*)(smem + 32768);                      // 6 bufs x 4096 f16 (8KB)
    f16* Cl = (f16*)smem;                                // aliased epilogue buf

    int tid = threadIdx.x, lane = tid & 63, wid = tid >> 6;
    int quad = lane >> 4, l15 = lane & 15;

    // XCD-aware remap (bijective): L = y*64 + x; xcd = L&7 owns m-tiles
    // xcd*8..xcd*8+7 across all 36 y (y varies slowest within the XCD).
    int L = blockIdx.x + (blockIdx.y << 6);
    int xcd = L & 7, W = L >> 3;
    int mt = xcd * 8 + (W & 7);
    int yy = W >> 3;                                     // 0..35
    int m0 = mt * 128;
    int grp = yy / 6;
    if (grp == 3 && (m0 & 4095) != 0) return;            // qg: only s<32 tiles matter
    int nb = (yy - grp * 6) * 128;
    int wm = (wid >> 1) * 64, wn = (wid & 1) * 64;
    const f16* arow0 = Xh + (size_t)m0 * 768;
    const f16* brow0 = Wt + (size_t)(grp * 768 + nb) * 768;

    float4v acc[4][4];
#pragma unroll
    for (int mtt = 0; mtt < 4; ++mtt)
#pragma unroll
        for (int ntt = 0; ntt < 4; ++ntt) acc[mtt][ntt] = (float4v){0.f, 0.f, 0.f, 0.f};

    // Staging geometry + XOR swizzle (verified R13): thread s stages 16B chunk
    // (row = s>>2, lds slot s&3 holds global chunk (s&3)^((row>>1)&3)); read
    // side uses slot quad^((l15>>1)&3).
    int s0 = tid, s1 = tid + 256;
    int r0 = s0 >> 2, r1 = s1 >> 2;
    int o0 = (((s0 & 3) ^ ((r0 >> 1) & 3)) << 3);
    int o1 = (((s1 & 3) ^ ((r1 >> 1) & 3)) << 3);
    int sw8 = ((quad ^ ((l15 >> 1) & 3)) << 3);          // read-side slot (f16 units)

    auto STAGE_A = [&](int kt, int buf) {
        int k0 = kt << 5;
        gl_lds16(&arow0[(size_t)r0 * 768 + k0 + o0], As + buf * 4096 + wid * 512);
        gl_lds16(&arow0[(size_t)r1 * 768 + k0 + o1], As + buf * 4096 + 2048 + wid * 512);
    };
    auto STAGE_B = [&](int kt, int buf) {
        int k0 = kt << 5;
        gl_lds16(&brow0[(size_t)r0 * 768 + k0 + o0], Bs + buf * 4096 + wid * 512);
        gl_lds16(&brow0[(size_t)r1 * 768 + k0 + o1], Bs + buf * 4096 + 2048 + wid * 512);
    };

    // Per tile t: vmcnt(N) -> barrier -> stage A(t+3) [ring4], B(t+5) [ring6]
    // -> 8 ds_read_b128 -> setprio1 -> 16 MFMA -> setprio0.
    // Steady-state N=10: newer-than-A(t) = {B(t+2),A(t+1),B(t+3),A(t+2),
    // B(t+4)} = 10 loads; B(t) is older than A(t) (issued at t-5). Buffer
    // reuse safe: A-buf (t+3)&3 = (t-1)&3 and B-buf (t+5)%6 = (t-1)%6 were
    // last ds_read during tile t-1; those reads retired (lgkm before MFMA,
    // MFMA before barrier) before this tile's barrier; stage issues after.
#define QTILE(T, WN)                                                          \
    do {                                                                      \
        asm volatile("s_waitcnt vmcnt(" #WN ")" ::: "memory");                \
        __builtin_amdgcn_s_barrier();                                         \
        __builtin_amdgcn_sched_barrier(0);                                    \
        if ((T) + 3 <= 23) STAGE_A((T) + 3, ((T) + 3) & 3);                   \
        if ((T) + 5 <= 23) STAGE_B((T) + 5, ((T) + 5) % 6);                   \
        const f16* Ab = As + ((T) & 3) * 4096;                                \
        const f16* Bb = Bs + ((T) % 6) * 4096;                                \
        f16x8 af[4], bf[4];                                                   \
        _Pragma("unroll") for (int i = 0; i < 4; ++i)                         \
            af[i] = *(const f16x8*)&Ab[(wm + i * 16 + l15) * 32 + sw8];       \
        _Pragma("unroll") for (int j = 0; j < 4; ++j)                         \
            bf[j] = *(const f16x8*)&Bb[(wn + j * 16 + l15) * 32 + sw8];       \
        __builtin_amdgcn_s_setprio(1);                                        \
        _Pragma("unroll") for (int i = 0; i < 4; ++i)                         \
            _Pragma("unroll") for (int j = 0; j < 4; ++j)                     \
                acc[i][j] = mfma16(af[i], bf[j], acc[i][j]);                  \
        __builtin_amdgcn_s_setprio(0);                                        \
    } while (0)

    STAGE_A(0, 0); STAGE_A(1, 1); STAGE_A(2, 2);
    STAGE_B(0, 0); STAGE_B(1, 1); STAGE_B(2, 2); STAGE_B(3, 3); STAGE_B(4, 4);
    QTILE(0, 8);
    QTILE(1, 10);  QTILE(2, 10);  QTILE(3, 10);  QTILE(4, 10);  QTILE(5, 10);
    QTILE(6, 10);  QTILE(7, 10);  QTILE(8, 10);  QTILE(9, 10);  QTILE(10, 10);
    QTILE(11, 10); QTILE(12, 10); QTILE(13, 10); QTILE(14, 10); QTILE(15, 10);
    QTILE(16, 10); QTILE(17, 10); QTILE(18, 10); QTILE(19, 10);
    QTILE(20, 8);
    QTILE(21, 6);
    QTILE(22, 2);
    QTILE(23, 0);
#undef QTILE
    __syncthreads();   // all waves done with A/B rings before Cl overwrites

    const float* Bsel = (grp == 0) ? b0 : (grp == 1) ? b1 : (grp == 2) ? b2
                      : (grp == 3) ? b3 : (grp == 4) ? b4 : b5;
    int b = m0 >> 12;
    bool tr = (grp == 2 || grp == 5);

    if (tr) {
#pragma unroll
        for (int nt = 0; nt < 4; ++nt) {
            float bias = Bsel[nb + wn + nt * 16 + l15];
#pragma unroll
            for (int mtt = 0; mtt < 4; ++mtt) {
                float4v a = acc[mtt][nt];
                h4 pk = {(f16)(a[0] + bias), (f16)(a[1] + bias),
                         (f16)(a[2] + bias), (f16)(a[3] + bias)};
                *(h4*)&Cl[(wn + nt * 16 + l15) * CLD + wm + mtt * 16 + quad * 4] = pk;
            }
        }
    } else {
        float scale = (grp == 0 || grp == 3) ? 0.125f : 1.0f;
#pragma unroll
        for (int nt = 0; nt < 4; ++nt) {
            float bias = Bsel[nb + wn + nt * 16 + l15];
#pragma unroll
            for (int mtt = 0; mtt < 4; ++mtt) {
                float4v a = acc[mtt][nt];
#pragma unroll
                for (int r = 0; r < 4; ++r)
                    Cl[(wm + mtt * 16 + quad * 4 + r) * CLD + wn + nt * 16 + l15] =
                        (f16)((a[r] + bias) * scale);
            }
        }
    }
    __syncthreads();

    if (tr) {
        f16* base = (grp == 2) ? vT : vgT;
        int c = tid & 127, sh = (tid >> 7) * 64;
        int ncol = nb + c, h = ncol >> 6, hd = ncol & 63;
        f16* dst = &base[((size_t)((b * 12 + h) * 64 + hd)) * 4096 + (m0 & 4095) + sh];
        const f16* src = &Cl[c * CLD + sh];
#pragma unroll
        for (int i = 0; i < 8; ++i)
            *(f16x8*)&dst[i * 8] = *(const f16x8*)&src[i * 8];
    } else {
        int sl = tid & 127, hh = tid >> 7;
        int s = (m0 & 4095) + sl;
        int h = (nb + hh * 64) >> 6;
        const f16* src = &Cl[sl * CLD + hh * 64];
        f16* dst = nullptr;
        if (grp == 3) {
            if (s < 32) dst = &qg[((size_t)((b * 12 + h) * 32 + s)) * 64];
        } else {
            f16* baseb = (grp == 0) ? q : (grp == 1) ? k : kg;
            dst = &baseb[((size_t)((b * 12 + h) * 4096 + s)) * 64];
        }
        if (dst)
#pragma unroll
            for (int i = 0; i < 8; ++i)
                *(f16x8*)&dst[i * 8] = *(const f16x8*)&src[i * 8];
    }
}

// ---------------------------------------------------------------------------
// band_mfma5 — unchanged from R11 (proven).
// ---------------------------------------------------------------------------
__global__ __launch_bounds__(256, 3) void band_mfma5(
    const f16* __restrict__ q, const f16* __restrict__ k, const f16* __restrict__ vT,
    float* __restrict__ out) {
    constexpr int LDK = 72, LDV = 136, LDP = 40;
    __shared__ __align__(16) f16 Kt[128 * LDK];
    __shared__ __align__(16) f16 Vt[64 * LDV];
    __shared__ __align__(16) f16 Pt[4][32 * LDP];
    int tid = threadIdx.x, lane = tid & 63, wid = tid >> 6;
    int quad = lane >> 4, l15 = lane & 15;
    int c = blockIdx.x & 31, h = (blockIdx.x >> 5) % 12, b = blockIdx.x / 384;
    const f16* qsl = q + (size_t)(b * 12 + h) * 4096 * 64;
    const f16* ksl = k + (size_t)(b * 12 + h) * 4096 * 64;
    const f16* vsl = vT + (size_t)(b * 12 + h) * 64 * 4096;
    int q0 = c * 128;
    int pq0 = q0 + wid * 32;

    f16x8 qf[2][2];
#pragma unroll
    for (int qg = 0; qg < 2; ++qg)
#pragma unroll
        for (int ks = 0; ks < 2; ++ks)
            qf[qg][ks] = *(const f16x8*)&qsl[(size_t)(pq0 + qg * 16 + l15) * 64 +
                                             ks * 32 + quad * 8];

    float4v Ot[4][2];
#pragma unroll
    for (int dt = 0; dt < 4; ++dt)
#pragma unroll
        for (int qg = 0; qg < 2; ++qg) Ot[dt][qg] = (float4v){0.f, 0.f, 0.f, 0.f};
    float lacc[2] = {0.f, 0.f};
    f16* PW = &Pt[wid][0];

    {
#pragma unroll
        for (int jt = 0; jt < 2; ++jt) {
            f16x8 kf0 = *(const f16x8*)&ksl[(size_t)(jt * 16 + l15) * 64 + quad * 8];
            f16x8 kf1 = *(const f16x8*)&ksl[(size_t)(jt * 16 + l15) * 64 + 32 + quad * 8];
#pragma unroll
            for (int qg = 0; qg < 2; ++qg) {
                float4v sacc = (float4v){0.f, 0.f, 0.f, 0.f};
                sacc = mfma16(kf0, qf[qg][0], sacc);
                sacc = mfma16(kf1, qf[qg][1], sacc);
                float p0 = __expf(sacc[0]), p1 = __expf(sacc[1]);
                float p2 = __expf(sacc[2]), p3 = __expf(sacc[3]);
                lacc[qg] += (p0 + p1) + (p2 + p3);
                h4 pk = {(f16)p0, (f16)p1, (f16)p2, (f16)p3};
                *(h4*)&PW[(qg * 16 + l15) * LDP + jt * 16 + quad * 4] = pk;
            }
        }
        f16x8 pf0 = *(const f16x8*)&PW[l15 * LDP + quad * 8];
        f16x8 pf1 = *(const f16x8*)&PW[(16 + l15) * LDP + quad * 8];
#pragma unroll
        for (int dt = 0; dt < 4; ++dt) {
            f16x8 vf = *(const f16x8*)&vsl[(size_t)(dt * 16 + l15) * 4096 + quad * 8];
            Ot[dt][0] = mfma16(vf, pf0, Ot[dt][0]);
            Ot[dt][1] = mfma16(vf, pf1, Ot[dt][1]);
        }
    }

    for (int r = 0; r < 5; ++r) {
        int kb = q0 - 256 + r * 128;
        if (kb < 0 || kb >= 4096) continue;
        __syncthreads();
        {
            int kr = tid >> 1, ko = (tid & 1) * 32;
            const f16* ks2 = &ksl[(size_t)(kb + kr) * 64 + ko];
            f16* kd = &Kt[kr * LDK + ko];
#pragma unroll
            for (int i = 0; i < 4; ++i) *(f16x8*)&kd[i * 8] = *(const f16x8*)&ks2[i * 8];
            int vr = tid >> 2, vo = (tid & 3) * 32;
            const f16* vs2 = &vsl[(size_t)vr * 4096 + kb + vo];
            f16* vd = &Vt[vr * LDV + vo];
#pragma unroll
            for (int i = 0; i < 4; ++i) *(f16x8*)&vd[i * 8] = *(const f16x8*)&vs2[i * 8];
        }
        __syncthreads();

        if (kb + 127 < pq0 - 256 || kb > pq0 + 287) continue;

#pragma unroll
        for (int tt = 0; tt < 2; ++tt) {
            int tb = kb + tt * 64;
            if (tb + 63 < pq0 - 256 || tb > pq0 + 287) continue;
#pragma unroll
            for (int hf = 0; hf < 2; ++hf) {
#pragma unroll
                for (int jt = 0; jt < 2; ++jt) {
                    int jl = tt * 64 + hf * 32 + jt * 16;
                    f16x8 kf0 = *(const f16x8*)&Kt[(jl + l15) * LDK + quad * 8];
                    f16x8 kf1 = *(const f16x8*)&Kt[(jl + l15) * LDK + 32 + quad * 8];
                    int j0 = kb + jl;
#pragma unroll
                    for (int qg = 0; qg < 2; ++qg) {
                        int qlo = pq0 + qg * 16;
                        h4 pk = {(f16)0.f, (f16)0.f, (f16)0.f, (f16)0.f};
                        bool dead = (j0 < qlo - 271) || (j0 > qlo + 271);
                        if (!dead) {
                            float4v sacc = (float4v){0.f, 0.f, 0.f, 0.f};
                            sacc = mfma16(kf0, qf[qg][0], sacc);
                            sacc = mfma16(kf1, qf[qg][1], sacc);
                            float p[4];
                            bool full = (j0 >= qlo - 241) && (j0 <= qlo + 241);
                            if (full) {
#pragma unroll
                                for (int rr = 0; rr < 4; ++rr) p[rr] = __expf(sacc[rr]);
                            } else {
#pragma unroll
                                for (int rr = 0; rr < 4; ++rr) {
                                    int d = (j0 + quad * 4 + rr) - (qlo + l15);
                                    p[rr] = ((unsigned)(d + 256) <= 512u) ? __expf(sacc[rr]) : 0.f;
                                }
                            }
                            lacc[qg] += (p[0] + p[1]) + (p[2] + p[3]);
                            pk = (h4){(f16)p[0], (f16)p[1], (f16)p[2], (f16)p[3]};
                        }
                        *(h4*)&PW[(qg * 16 + l15) * LDP + jt * 16 + quad * 4] = pk;
                    }
                }
                f16x8 pf0 = *(const f16x8*)&PW[l15 * LDP + quad * 8];
                f16x8 pf1 = *(const f16x8*)&PW[(16 + l15) * LDP + quad * 8];
#pragma unroll
                for (int dt = 0; dt < 4; ++dt) {
                    f16x8 vf = *(const f16x8*)&Vt[(dt * 16 + l15) * LDV +
                                                  tt * 64 + hf * 32 + quad * 8];
                    Ot[dt][0] = mfma16(vf, pf0, Ot[dt][0]);
                    Ot[dt][1] = mfma16(vf, pf1, Ot[dt][1]);
                }
            }
        }
    }

#pragma unroll
    for (int qg = 0; qg < 2; ++qg) {
        float lsum = lacc[qg];
        lsum += __shfl_xor(lsum, 16);
        lsum += __shfl_xor(lsum, 32);
        float inv = 1.f / lsum;
        size_t orow = (size_t)(b * 4096 + pq0 + qg * 16 + l15) * 768 + h * 64;
#pragma unroll
        for (int dt = 0; dt < 4; ++dt) {
            float4 o4 = {Ot[dt][qg][0] * inv, Ot[dt][qg][1] * inv,
                         Ot[dt][qg][2] * inv, Ot[dt][qg][3] * inv};
            *(float4*)&out[orow + dt * 16 + quad * 4] = o4;
        }
    }
}

// ---------------------------------------------------------------------------
// global_part / global_reduce — unchanged from R11 (proven).
// ---------------------------------------------------------------------------
__global__ __launch_bounds__(256) void global_part(
    const f16* __restrict__ qg, const f16* __restrict__ kg, const f16* __restrict__ vgT,
    float* __restrict__ Opart, float* __restrict__ Lpart) {
    constexpr int LDP = 72;
    __shared__ __align__(16) f16 Pt[4][32 * LDP];
    __shared__ __align__(16) float Osh[4][64 * 32];
    __shared__ float Lsh[4][32];
    int tid = threadIdx.x, lane = tid & 63, wid = tid >> 6;
    int quad = lane >> 4, l15 = lane & 15;
    int sl = blockIdx.x & 7, bh = blockIdx.x >> 3;
    const f16* qsl = qg + (size_t)bh * 32 * 64;
    const f16* ksl = kg + (size_t)bh * 4096 * 64;
    const f16* vsl = vgT + (size_t)bh * 64 * 4096;
    int kbase = sl * 512 + wid * 128;

    f16x8 qf[2][2];
#pragma unroll
    for (int g = 0; g < 2; ++g)
#pragma unroll
        for (int ks = 0; ks < 2; ++ks)
            qf[g][ks] = *(const f16x8*)&qsl[(size_t)(g * 16 + l15) * 64 + ks * 32 + quad * 8];

    float4v Ot[4][2];
#pragma unroll
    for (int dt = 0; dt < 4; ++dt)
#pragma unroll
        for (int g = 0; g < 2; ++g) Ot[dt][g] = (float4v){0.f, 0.f, 0.f, 0.f};
    float lacc[2] = {0.f, 0.f};
    f16* PW = &Pt[wid][0];

#pragma unroll
    for (int hf = 0; hf < 2; ++hf) {
        int kh0 = kbase + hf * 64;
#pragma unroll
        for (int kt = 0; kt < 4; ++kt) {
            int jb = kh0 + kt * 16;
            f16x8 kf0 = *(const f16x8*)&ksl[(size_t)(jb + l15) * 64 + quad * 8];
            f16x8 kf1 = *(const f16x8*)&ksl[(size_t)(jb + l15) * 64 + 32 + quad * 8];
#pragma unroll
            for (int g = 0; g < 2; ++g) {
                float4v sacc = (float4v){0.f, 0.f, 0.f, 0.f};
                sacc = mfma16(kf0, qf[g][0], sacc);
                sacc = mfma16(kf1, qf[g][1], sacc);
                float p0 = __expf(sacc[0]), p1 = __expf(sacc[1]);
                float p2 = __expf(sacc[2]), p3 = __expf(sacc[3]);
                lacc[g] += (p0 + p1) + (p2 + p3);
                h4 pk = {(f16)p0, (f16)p1, (f16)p2, (f16)p3};
                *(h4*)&PW[(g * 16 + l15) * LDP + kt * 16 + quad * 4] = pk;
            }
        }
#pragma unroll
        for (int kh = 0; kh < 2; ++kh) {
            f16x8 pf0 = *(const f16x8*)&PW[l15 * LDP + kh * 32 + quad * 8];
            f16x8 pf1 = *(const f16x8*)&PW[(16 + l15) * LDP + kh * 32 + quad * 8];
#pragma unroll
            for (int dt = 0; dt < 4; ++dt) {
                f16x8 vf = *(const f16x8*)&vsl[(size_t)(dt * 16 + l15) * 4096 +
                                               kh0 + kh * 32 + quad * 8];
                Ot[dt][0] = mfma16(vf, pf0, Ot[dt][0]);
                Ot[dt][1] = mfma16(vf, pf1, Ot[dt][1]);
            }
        }
    }

#pragma unroll
    for (int g = 0; g < 2; ++g) {
        lacc[g] += __shfl_xor(lacc[g], 16);
        lacc[g] += __shfl_xor(lacc[g], 32);
    }
    if (quad == 0) { Lsh[wid][l15] = lacc[0]; Lsh[wid][16 + l15] = lacc[1]; }
#pragma unroll
    for (int dt = 0; dt < 4; ++dt)
#pragma unroll
        for (int g = 0; g < 2; ++g)
#pragma unroll
            for (int r = 0; r < 4; ++r)
                Osh[wid][(dt * 16 + quad * 4 + r) * 32 + g * 16 + l15] = Ot[dt][g][r];
    __syncthreads();
#pragma unroll
    for (int i = 0; i < 8; ++i) {
        int idx = tid + i * 256;
        int d = idx & 63, qq = idx >> 6;
        float v = Osh[0][d * 32 + qq] + Osh[1][d * 32 + qq] +
                  Osh[2][d * 32 + qq] + Osh[3][d * 32 + qq];
        Opart[(size_t)blockIdx.x * 2048 + idx] = v;
    }
    if (tid < 32)
        Lpart[blockIdx.x * 32 + tid] = Lsh[0][tid] + Lsh[1][tid] + Lsh[2][tid] + Lsh[3][tid];
}

__global__ __launch_bounds__(256) void global_reduce(
    const float* __restrict__ Opart, const float* __restrict__ Lpart,
    float* __restrict__ out) {
    __shared__ float Ls[32];
    int tid = threadIdx.x, bh = blockIdx.x;
    int b = bh / 12, h = bh % 12;
    if (tid < 32) {
        float s = 0.f;
#pragma unroll
        for (int sl = 0; sl < 8; ++sl) s += Lpart[(bh * 8 + sl) * 32 + tid];
        Ls[tid] = s;
    }
    __syncthreads();
#pragma unroll
    for (int i = 0; i < 8; ++i) {
        int idx = tid + i * 256;
        int d = idx & 63, qq = idx >> 6;
        float o = 0.f;
#pragma unroll
        for (int sl = 0; sl < 8; ++sl) o += Opart[(size_t)(bh * 8 + sl) * 2048 + idx];
        out[(size_t)(b * 4096 + qq) * 768 + h * 64 + d] = o / Ls[qq];
    }
}

// ---------------------------------------------------------------------------
extern "C" void kernel_launch(void* const* d_in, const int* in_sizes, int n_in,
                              void* d_out, int out_size, void* d_ws, size_t ws_size,
                              hipStream_t stream) {
    const float* hs = (const float*)d_in[0];
    float* outp = (float*)d_out;

    char* p = (char*)d_ws;
    const size_t SLAB = (size_t)2 * 12 * 4096 * 64 * sizeof(f16);   // 12,582,912 B
    f16* qb   = (f16*)(p + 0 * SLAB);
    f16* kb   = (f16*)(p + 1 * SLAB);
    f16* vtb  = (f16*)(p + 2 * SLAB);   // [bh][d][s]
    f16* kgb  = (f16*)(p + 3 * SLAB);
    f16* vgtb = (f16*)(p + 4 * SLAB);   // [bh][d][s]
    f16* qgb  = (f16*)(p + 5 * SLAB);
    char* p2  = p + 5 * SLAB + 196608;
    f16* xh   = (f16*)p2;
    f16* wt   = (f16*)(p2 + SLAB);
    char* p3  = p2 + SLAB + 7077888;
    float* Opart = (float*)p3;
    float* Lpart = (float*)(p3 + 1572864);

    prep<<<7008, 256, 0, stream>>>(
        hs,
        (const float*)d_in[1], (const float*)d_in[3], (const float*)d_in[5],
        (const float*)d_in[7], (const float*)d_in[9], (const float*)d_in[11],
        xh, wt);
    qkv_mfma8<<<dim3(64, 36), 256, 0, stream>>>(
        xh, wt,
        (const float*)d_in[2], (const float*)d_in[4], (const float*)d_in[6],
        (const float*)d_in[8], (const float*)d_in[10], (const float*)d_in[12],
        qb, kb, vtb, qgb, kgb, vgtb);
    band_mfma5<<<768, 256, 0, stream>>>(qb, kb, vtb, outp);
    global_part<<<192, 256, 0, stream>>>(qgb, kgb, vgtb, Opart, Lpart);
    global_reduce<<<24, 256, 0, stream>>>(Opart, Lpart, outp);
}

// Round 5
// 222.057 us; speedup vs baseline: 1.0400x; 1.0134x over previous
//
#include <hip/hip_runtime.h>
#include <hip/hip_bf16.h>

// Longformer self-attention, MI355X gfx950 — ROUND 17.
// fp32 I/O, f16 intermediates. Changes vs R16 (single variable — TLP test):
//  (1) qkv_mfma9: rings cut from 4A+6B (80KB, 2 blocks/CU) to 3A+3B
//      (48KB -> 3 blocks/CU, 12 waves/CU = 3/SIMD). R16's counters (all
//      pipes <25%, occ 17.7%) say latency-bound with too few waves to
//      cover the per-tile barrier/vmcnt wait; this trades prefetch depth
//      (5->2 tiles) for +50% TLP. Depth-2 still covers ~1600cy at the
//      measured ~800cy/tile/block interval. Steady vmcnt(4) retires
//      exactly tile t's 4 loads; t+1/t+2 stay in flight across barriers.
//      Keeps ALL proven bits: XCD remap (FETCH 45->36MB), XOR swizzle
//      (conflicts 6.1M->197K), counted vmcnt, setprio.
// prep / band_mfma5 / global_part / global_reduce unchanged (proven).

#define DEVI __device__ __forceinline__
typedef _Float16 f16;
typedef _Float16 h4 __attribute__((ext_vector_type(4)));
typedef _Float16 f16x8 __attribute__((ext_vector_type(8)));
typedef __attribute__((ext_vector_type(4))) float float4v;

DEVI float4v mfma16(f16x8 a, f16x8 b, float4v c) {
    return __builtin_amdgcn_mfma_f32_16x16x32_f16(a, b, c, 0, 0, 0);
}

DEVI void gl_lds16(const f16* g, f16* l) {
    __builtin_amdgcn_global_load_lds(
        (const __attribute__((address_space(1))) unsigned int*)g,
        (__attribute__((address_space(3))) unsigned int*)l, 16, 0, 0);
}

// ---------------------------------------------------------------------------
// prep: blocks [0,6144) = xcast (fp32->f16, 8192*768); blocks [6144,7008) =
// weight transpose Wt[i*768+n][k] = (f16) W_i[k][n].
// ---------------------------------------------------------------------------
__global__ __launch_bounds__(256) void prep(
    const float* __restrict__ x,
    const float* __restrict__ w0, const float* __restrict__ w1,
    const float* __restrict__ w2, const float* __restrict__ w3,
    const float* __restrict__ w4, const float* __restrict__ w5,
    f16* __restrict__ xh, f16* __restrict__ wt) {
    __shared__ float tile[64][65];
    int bid = blockIdx.x;
    if (bid < 6144) {
        int i = (bid * 256 + threadIdx.x) * 4;
        float4 v = *(const float4*)&x[i];
        h4 o = {(f16)v.x, (f16)v.y, (f16)v.z, (f16)v.w};
        *(h4*)&xh[i] = o;
    } else {
        int t = bid - 6144;
        int i = t / 144, rem = t - i * 144;
        int n0 = (rem % 12) * 64, k0 = (rem / 12) * 64;
        const float* W = (i == 0) ? w0 : (i == 1) ? w1 : (i == 2) ? w2
                       : (i == 3) ? w3 : (i == 4) ? w4 : w5;
        int tx = threadIdx.x & 63, ty = threadIdx.x >> 6;
#pragma unroll
        for (int yy = 0; yy < 64; yy += 4)
            tile[yy + ty][tx] = W[(size_t)(k0 + yy + ty) * 768 + n0 + tx];
        __syncthreads();
#pragma unroll
        for (int yy = 0; yy < 64; yy += 4)
            wt[(size_t)(i * 768 + n0 + yy + ty) * 768 + k0 + tx] = (f16)tile[tx][yy + ty];
    }
}

// ---------------------------------------------------------------------------
// qkv_mfma9: R16 skeleton, rings 3A+3B (48KB) -> 3 blocks/CU.
// ---------------------------------------------------------------------------
__global__ __launch_bounds__(256) void qkv_mfma9(
    const f16* __restrict__ Xh, const f16* __restrict__ Wt,
    const float* __restrict__ b0, const float* __restrict__ b1,
    const float* __restrict__ b2, const float* __restrict__ b3,
    const float* __restrict__ b4, const float* __restrict__ b5,
    f16* __restrict__ q, f16* __restrict__ k, f16* __restrict__ vT,
    f16* __restrict__ qg, f16* __restrict__ kg, f16* __restrict__ vgT) {
    constexpr int CLD = 136;
    __shared__ __align__(16) char smem[49152];           // 24KB A-ring + 24KB B-ring
    f16* As = (f16*)smem;                                // 3 bufs x 4096 f16 (8KB)
    f16* Bs = (f16*)(smem + 24576);                      // 3 bufs x 4096 f16 (8KB)
    f16* Cl = (f16*)smem;                                // aliased epilogue buf

    int tid = threadIdx.x, lane = tid & 63, wid = tid >> 6;
    int quad = lane >> 4, l15 = lane & 15;

    // XCD-aware remap (bijective, verified R16): L = y*64 + x; xcd = L&7
    // owns m-tiles xcd*8..xcd*8+7 across all 36 y (y slowest in XCD).
    int L = blockIdx.x + (blockIdx.y << 6);
    int xcd = L & 7, W = L >> 3;
    int mt = xcd * 8 + (W & 7);
    int yy = W >> 3;                                     // 0..35
    int m0 = mt * 128;
    int grp = yy / 6;
    if (grp == 3 && (m0 & 4095) != 0) return;            // qg: only s<32 tiles matter
    int nb = (yy - grp * 6) * 128;
    int wm = (wid >> 1) * 64, wn = (wid & 1) * 64;
    const f16* arow0 = Xh + (size_t)m0 * 768;
    const f16* brow0 = Wt + (size_t)(grp * 768 + nb) * 768;

    float4v acc[4][4];
#pragma unroll
    for (int mtt = 0; mtt < 4; ++mtt)
#pragma unroll
        for (int ntt = 0; ntt < 4; ++ntt) acc[mtt][ntt] = (float4v){0.f, 0.f, 0.f, 0.f};

    // Staging geometry + XOR swizzle (verified R13): thread s stages 16B chunk
    // (row = s>>2, lds slot s&3 holds global chunk (s&3)^((row>>1)&3)); read
    // side uses slot quad^((l15>>1)&3).
    int s0 = tid, s1 = tid + 256;
    int r0 = s0 >> 2, r1 = s1 >> 2;
    int o0 = (((s0 & 3) ^ ((r0 >> 1) & 3)) << 3);
    int o1 = (((s1 & 3) ^ ((r1 >> 1) & 3)) << 3);
    int sw8 = ((quad ^ ((l15 >> 1) & 3)) << 3);          // read-side slot (f16 units)

    // One tile's staging = 4 VMEM instrs/wave, issued A,A,B,B (tile-granular
    // retire order).
    auto STAGE_T = [&](int kt, int buf) {
        int k0 = kt << 5;
        gl_lds16(&arow0[(size_t)r0 * 768 + k0 + o0], As + buf * 4096 + wid * 512);
        gl_lds16(&arow0[(size_t)r1 * 768 + k0 + o1], As + buf * 4096 + 2048 + wid * 512);
        gl_lds16(&brow0[(size_t)r0 * 768 + k0 + o0], Bs + buf * 4096 + wid * 512);
        gl_lds16(&brow0[(size_t)r1 * 768 + k0 + o1], Bs + buf * 4096 + 2048 + wid * 512);
    };

    // Per tile t: vmcnt(N) -> barrier -> stage(t+2) -> 8 ds_read_b128 ->
    // setprio1 -> 16 MFMA -> setprio0.
    // Steady N=4: outstanding before wait = S(t) 4 + S(t+1) 4; wait<=4
    // retires S(t) exactly; S(t+1) stays in flight across the barrier, and
    // S(t+2) is issued after it. Buffer reuse safe: (t+2)%3 == (t-1)%3 was
    // last ds_read during tile t-1; every wave's reads retired (lgkm before
    // its MFMAs) before it arrived at this tile's barrier; stage issues
    // after the barrier.
#define QTILE(T, WN)                                                          \
    do {                                                                      \
        asm volatile("s_waitcnt vmcnt(" #WN ")" ::: "memory");                \
        __builtin_amdgcn_s_barrier();                                         \
        __builtin_amdgcn_sched_barrier(0);                                    \
        if ((T) + 2 <= 23) STAGE_T((T) + 2, ((T) + 2) % 3);                   \
        const f16* Ab = As + ((T) % 3) * 4096;                                \
        const f16* Bb = Bs + ((T) % 3) * 4096;                                \
        f16x8 af[4], bf[4];                                                   \
        _Pragma("unroll") for (int i = 0; i < 4; ++i)                         \
            af[i] = *(const f16x8*)&Ab[(wm + i * 16 + l15) * 32 + sw8];       \
        _Pragma("unroll") for (int j = 0; j < 4; ++j)                         \
            bf[j] = *(const f16x8*)&Bb[(wn + j * 16 + l15) * 32 + sw8];       \
        __builtin_amdgcn_s_setprio(1);                                        \
        _Pragma("unroll") for (int i = 0; i < 4; ++i)                         \
            _Pragma("unroll") for (int j = 0; j < 4; ++j)                     \
                acc[i][j] = mfma16(af[i], bf[j], acc[i][j]);                  \
        __builtin_amdgcn_s_setprio(0);                                        \
    } while (0)

    STAGE_T(0, 0);
    STAGE_T(1, 1);
    QTILE(0, 4);
    QTILE(1, 4);  QTILE(2, 4);  QTILE(3, 4);  QTILE(4, 4);  QTILE(5, 4);
    QTILE(6, 4);  QTILE(7, 4);  QTILE(8, 4);  QTILE(9, 4);  QTILE(10, 4);
    QTILE(11, 4); QTILE(12, 4); QTILE(13, 4); QTILE(14, 4); QTILE(15, 4);
    QTILE(16, 4); QTILE(17, 4); QTILE(18, 4); QTILE(19, 4); QTILE(20, 4);
    QTILE(21, 4);
    QTILE(22, 4);
    QTILE(23, 0);
#undef QTILE
    __syncthreads();   // all waves done with A/B rings before Cl overwrites

    const float* Bsel = (grp == 0) ? b0 : (grp == 1) ? b1 : (grp == 2) ? b2
                      : (grp == 3) ? b3 : (grp == 4) ? b4 : b5;
    int b = m0 >> 12;
    bool tr = (grp == 2 || grp == 5);

    if (tr) {
#pragma unroll
        for (int nt = 0; nt < 4; ++nt) {
            float bias = Bsel[nb + wn + nt * 16 + l15];
#pragma unroll
            for (int mtt = 0; mtt < 4; ++mtt) {
                float4v a = acc[mtt][nt];
                h4 pk = {(f16)(a[0] + bias), (f16)(a[1] + bias),
                         (f16)(a[2] + bias), (f16)(a[3] + bias)};
                *(h4*)&Cl[(wn + nt * 16 + l15) * CLD + wm + mtt * 16 + quad * 4] = pk;
            }
        }
    } else {
        float scale = (grp == 0 || grp == 3) ? 0.125f : 1.0f;
#pragma unroll
        for (int nt = 0; nt < 4; ++nt) {
            float bias = Bsel[nb + wn + nt * 16 + l15];
#pragma unroll
            for (int mtt = 0; mtt < 4; ++mtt) {
                float4v a = acc[mtt][nt];
#pragma unroll
                for (int r = 0; r < 4; ++r)
                    Cl[(wm + mtt * 16 + quad * 4 + r) * CLD + wn + nt * 16 + l15] =
                        (f16)((a[r] + bias) * scale);
            }
        }
    }
    __syncthreads();

    if (tr) {
        f16* base = (grp == 2) ? vT : vgT;
        int c = tid & 127, sh = (tid >> 7) * 64;
        int ncol = nb + c, h = ncol >> 6, hd = ncol & 63;
        f16* dst = &base[((size_t)((b * 12 + h) * 64 + hd)) * 4096 + (m0 & 4095) + sh];
        const f16* src = &Cl[c * CLD + sh];
#pragma unroll
        for (int i = 0; i < 8; ++i)
            *(f16x8*)&dst[i * 8] = *(const f16x8*)&src[i * 8];
    } else {
        int sl = tid & 127, hh = tid >> 7;
        int s = (m0 & 4095) + sl;
        int h = (nb + hh * 64) >> 6;
        const f16* src = &Cl[sl * CLD + hh * 64];
        f16* dst = nullptr;
        if (grp == 3) {
            if (s < 32) dst = &qg[((size_t)((b * 12 + h) * 32 + s)) * 64];
        } else {
            f16* baseb = (grp == 0) ? q : (grp == 1) ? k : kg;
            dst = &baseb[((size_t)((b * 12 + h) * 4096 + s)) * 64];
        }
        if (dst)
#pragma unroll
            for (int i = 0; i < 8; ++i)
                *(f16x8*)&dst[i * 8] = *(const f16x8*)&src[i * 8];
    }
}

// ---------------------------------------------------------------------------
// band_mfma5 — unchanged from R11 (proven).
// ---------------------------------------------------------------------------
__global__ __launch_bounds__(256, 3) void band_mfma5(
    const f16* __restrict__ q, const f16* __restrict__ k, const f16* __restrict__ vT,
    float* __restrict__ out) {
    constexpr int LDK = 72, LDV = 136, LDP = 40;
    __shared__ __align__(16) f16 Kt[128 * LDK];
    __shared__ __align__(16) f16 Vt[64 * LDV];
    __shared__ __align__(16) f16 Pt[4][32 * LDP];
    int tid = threadIdx.x, lane = tid & 63, wid = tid >> 6;
    int quad = lane >> 4, l15 = lane & 15;
    int c = blockIdx.x & 31, h = (blockIdx.x >> 5) % 12, b = blockIdx.x / 384;
    const f16* qsl = q + (size_t)(b * 12 + h) * 4096 * 64;
    const f16* ksl = k + (size_t)(b * 12 + h) * 4096 * 64;
    const f16* vsl = vT + (size_t)(b * 12 + h) * 64 * 4096;
    int q0 = c * 128;
    int pq0 = q0 + wid * 32;

    f16x8 qf[2][2];
#pragma unroll
    for (int qg = 0; qg < 2; ++qg)
#pragma unroll
        for (int ks = 0; ks < 2; ++ks)
            qf[qg][ks] = *(const f16x8*)&qsl[(size_t)(pq0 + qg * 16 + l15) * 64 +
                                             ks * 32 + quad * 8];

    float4v Ot[4][2];
#pragma unroll
    for (int dt = 0; dt < 4; ++dt)
#pragma unroll
        for (int qg = 0; qg < 2; ++qg) Ot[dt][qg] = (float4v){0.f, 0.f, 0.f, 0.f};
    float lacc[2] = {0.f, 0.f};
    f16* PW = &Pt[wid][0];

    {
#pragma unroll
        for (int jt = 0; jt < 2; ++jt) {
            f16x8 kf0 = *(const f16x8*)&ksl[(size_t)(jt * 16 + l15) * 64 + quad * 8];
            f16x8 kf1 = *(const f16x8*)&ksl[(size_t)(jt * 16 + l15) * 64 + 32 + quad * 8];
#pragma unroll
            for (int qg = 0; qg < 2; ++qg) {
                float4v sacc = (float4v){0.f, 0.f, 0.f, 0.f};
                sacc = mfma16(kf0, qf[qg][0], sacc);
                sacc = mfma16(kf1, qf[qg][1], sacc);
                float p0 = __expf(sacc[0]), p1 = __expf(sacc[1]);
                float p2 = __expf(sacc[2]), p3 = __expf(sacc[3]);
                lacc[qg] += (p0 + p1) + (p2 + p3);
                h4 pk = {(f16)p0, (f16)p1, (f16)p2, (f16)p3};
                *(h4*)&PW[(qg * 16 + l15) * LDP + jt * 16 + quad * 4] = pk;
            }
        }
        f16x8 pf0 = *(const f16x8*)&PW[l15 * LDP + quad * 8];
        f16x8 pf1 = *(const f16x8*)&PW[(16 + l15) * LDP + quad * 8];
#pragma unroll
        for (int dt = 0; dt < 4; ++dt) {
            f16x8 vf = *(const f16x8*)&vsl[(size_t)(dt * 16 + l15) * 4096 + quad * 8];
            Ot[dt][0] = mfma16(vf, pf0, Ot[dt][0]);
            Ot[dt][1] = mfma16(vf, pf1, Ot[dt][1]);
        }
    }

    for (int r = 0; r < 5; ++r) {
        int kb = q0 - 256 + r * 128;
        if (kb < 0 || kb >= 4096) continue;
        __syncthreads();
        {
            int kr = tid >> 1, ko = (tid & 1) * 32;
            const f16* ks2 = &ksl[(size_t)(kb + kr) * 64 + ko];
            f16* kd = &Kt[kr * LDK + ko];
#pragma unroll
            for (int i = 0; i < 4; ++i) *(f16x8*)&kd[i * 8] = *(const f16x8*)&ks2[i * 8];
            int vr = tid >> 2, vo = (tid & 3) * 32;
            const f16* vs2 = &vsl[(size_t)vr * 4096 + kb + vo];
            f16* vd = &Vt[vr * LDV + vo];
#pragma unroll
            for (int i = 0; i < 4; ++i) *(f16x8*)&vd[i * 8] = *(const f16x8*)&vs2[i * 8];
        }
        __syncthreads();

        if (kb + 127 < pq0 - 256 || kb > pq0 + 287) continue;

#pragma unroll
        for (int tt = 0; tt < 2; ++tt) {
            int tb = kb + tt * 64;
            if (tb + 63 < pq0 - 256 || tb > pq0 + 287) continue;
#pragma unroll
            for (int hf = 0; hf < 2; ++hf) {
#pragma unroll
                for (int jt = 0; jt < 2; ++jt) {
                    int jl = tt * 64 + hf * 32 + jt * 16;
                    f16x8 kf0 = *(const f16x8*)&Kt[(jl + l15) * LDK + quad * 8];
                    f16x8 kf1 = *(const f16x8*)&Kt[(jl + l15) * LDK + 32 + quad * 8];
                    int j0 = kb + jl;
#pragma unroll
                    for (int qg = 0; qg < 2; ++qg) {
                        int qlo = pq0 + qg * 16;
                        h4 pk = {(f16)0.f, (f16)0.f, (f16)0.f, (f16)0.f};
                        bool dead = (j0 < qlo - 271) || (j0 > qlo + 271);
                        if (!dead) {
                            float4v sacc = (float4v){0.f, 0.f, 0.f, 0.f};
                            sacc = mfma16(kf0, qf[qg][0], sacc);
                            sacc = mfma16(kf1, qf[qg][1], sacc);
                            float p[4];
                            bool full = (j0 >= qlo - 241) && (j0 <= qlo + 241);
                            if (full) {
#pragma unroll
                                for (int rr = 0; rr < 4; ++rr) p[rr] = __expf(sacc[rr]);
                            } else {
#pragma unroll
                                for (int rr = 0; rr < 4; ++rr) {
                                    int d = (j0 + quad * 4 + rr) - (qlo + l15);
                                    p[rr] = ((unsigned)(d + 256) <= 512u) ? __expf(sacc[rr]) : 0.f;
                                }
                            }
                            lacc[qg] += (p[0] + p[1]) + (p[2] + p[3]);
                            pk = (h4){(f16)p[0], (f16)p[1], (f16)p[2], (f16)p[3]};
                        }
                        *(h4*)&PW[(qg * 16 + l15) * LDP + jt * 16 + quad * 4] = pk;
                    }
                }
                f16x8 pf0 = *(const f16x8*)&PW[l15 * LDP + quad * 8];
                f16x8 pf1 = *(const f16x8*)&PW[(16 + l15) * LDP + quad * 8];
#pragma unroll
                for (int dt = 0; dt < 4; ++dt) {
                    f16x8 vf = *(const f16x8*)&Vt[(dt * 16 + l15) * LDV +
                                                  tt * 64 + hf * 32 + quad * 8];
                    Ot[dt][0] = mfma16(vf, pf0, Ot[dt][0]);
                    Ot[dt][1] = mfma16(vf, pf1, Ot[dt][1]);
                }
            }
        }
    }

#pragma unroll
    for (int qg = 0; qg < 2; ++qg) {
        float lsum = lacc[qg];
        lsum += __shfl_xor(lsum, 16);
        lsum += __shfl_xor(lsum, 32);
        float inv = 1.f / lsum;
        size_t orow = (size_t)(b * 4096 + pq0 + qg * 16 + l15) * 768 + h * 64;
#pragma unroll
        for (int dt = 0; dt < 4; ++dt) {
            float4 o4 = {Ot[dt][qg][0] * inv, Ot[dt][qg][1] * inv,
                         Ot[dt][qg][2] * inv, Ot[dt][qg][3] * inv};
            *(float4*)&out[orow + dt * 16 + quad * 4] = o4;
        }
    }
}

// ---------------------------------------------------------------------------
// global_part / global_reduce — unchanged from R11 (proven).
// ---------------------------------------------------------------------------
__global__ __launch_bounds__(256) void global_part(
    const f16* __restrict__ qg, const f16* __restrict__ kg, const f16* __restrict__ vgT,
    float* __restrict__ Opart, float* __restrict__ Lpart) {
    constexpr int LDP = 72;
    __shared__ __align__(16) f16 Pt[4][32 * LDP];
    __shared__ __align__(16) float Osh[4][64 * 32];
    __shared__ float Lsh[4][32];
    int tid = threadIdx.x, lane = tid & 63, wid = tid >> 6;
    int quad = lane >> 4, l15 = lane & 15;
    int sl = blockIdx.x & 7, bh = blockIdx.x >> 3;
    const f16* qsl = qg + (size_t)bh * 32 * 64;
    const f16* ksl = kg + (size_t)bh * 4096 * 64;
    const f16* vsl = vgT + (size_t)bh * 64 * 4096;
    int kbase = sl * 512 + wid * 128;

    f16x8 qf[2][2];
#pragma unroll
    for (int g = 0; g < 2; ++g)
#pragma unroll
        for (int ks = 0; ks < 2; ++ks)
            qf[g][ks] = *(const f16x8*)&qsl[(size_t)(g * 16 + l15) * 64 + ks * 32 + quad * 8];

    float4v Ot[4][2];
#pragma unroll
    for (int dt = 0; dt < 4; ++dt)
#pragma unroll
        for (int g = 0; g < 2; ++g) Ot[dt][g] = (float4v){0.f, 0.f, 0.f, 0.f};
    float lacc[2] = {0.f, 0.f};
    f16* PW = &Pt[wid][0];

#pragma unroll
    for (int hf = 0; hf < 2; ++hf) {
        int kh0 = kbase + hf * 64;
#pragma unroll
        for (int kt = 0; kt < 4; ++kt) {
            int jb = kh0 + kt * 16;
            f16x8 kf0 = *(const f16x8*)&ksl[(size_t)(jb + l15) * 64 + quad * 8];
            f16x8 kf1 = *(const f16x8*)&ksl[(size_t)(jb + l15) * 64 + 32 + quad * 8];
#pragma unroll
            for (int g = 0; g < 2; ++g) {
                float4v sacc = (float4v){0.f, 0.f, 0.f, 0.f};
                sacc = mfma16(kf0, qf[g][0], sacc);
                sacc = mfma16(kf1, qf[g][1], sacc);
                float p0 = __expf(sacc[0]), p1 = __expf(sacc[1]);
                float p2 = __expf(sacc[2]), p3 = __expf(sacc[3]);
                lacc[g] += (p0 + p1) + (p2 + p3);
                h4 pk = {(f16)p0, (f16)p1, (f16)p2, (f16)p3};
                *(h4*)&PW[(g * 16 + l15) * LDP + kt * 16 + quad * 4] = pk;
            }
        }
#pragma unroll
        for (int kh = 0; kh < 2; ++kh) {
            f16x8 pf0 = *(const f16x8*)&PW[l15 * LDP + kh * 32 + quad * 8];
            f16x8 pf1 = *(const f16x8*)&PW[(16 + l15) * LDP + kh * 32 + quad * 8];
#pragma unroll
            for (int dt = 0; dt < 4; ++dt) {
                f16x8 vf = *(const f16x8*)&vsl[(size_t)(dt * 16 + l15) * 4096 +
                                               kh0 + kh * 32 + quad * 8];
                Ot[dt][0] = mfma16(vf, pf0, Ot[dt][0]);
                Ot[dt][1] = mfma16(vf, pf1, Ot[dt][1]);
            }
        }
    }

#pragma unroll
    for (int g = 0; g < 2; ++g) {
        lacc[g] += __shfl_xor(lacc[g], 16);
        lacc[g] += __shfl_xor(lacc[g], 32);
    }
    if (quad == 0) { Lsh[wid][l15] = lacc[0]; Lsh[wid][16 + l15] = lacc[1]; }
#pragma unroll
    for (int dt = 0; dt < 4; ++dt)
#pragma unroll
        for (int g = 0; g < 2; ++g)
#pragma unroll
            for (int r = 0; r < 4; ++r)
                Osh[wid][(dt * 16 + quad * 4 + r) * 32 + g * 16 + l15] = Ot[dt][g][r];
    __syncthreads();
#pragma unroll
    for (int i = 0; i < 8; ++i) {
        int idx = tid + i * 256;
        int d = idx & 63, qq = idx >> 6;
        float v = Osh[0][d * 32 + qq] + Osh[1][d * 32 + qq] +
                  Osh[2][d * 32 + qq] + Osh[3][d * 32 + qq];
        Opart[(size_t)blockIdx.x * 2048 + idx] = v;
    }
    if (tid < 32)
        Lpart[blockIdx.x * 32 + tid] = Lsh[0][tid] + Lsh[1][tid] + Lsh[2][tid] + Lsh[3][tid];
}

__global__ __launch_bounds__(256) void global_reduce(
    const float* __restrict__ Opart, const float* __restrict__ Lpart,
    float* __restrict__ out) {
    __shared__ float Ls[32];
    int tid = threadIdx.x, bh = blockIdx.x;
    int b = bh / 12, h = bh % 12;
    if (tid < 32) {
        float s = 0.f;
#pragma unroll
        for (int sl = 0; sl < 8; ++sl) s += Lpart[(bh * 8 + sl) * 32 + tid];
        Ls[tid] = s;
    }
    __syncthreads();
#pragma unroll
    for (int i = 0; i < 8; ++i) {
        int idx = tid + i * 256;
        int d = idx & 63, qq = idx >> 6;
        float o = 0.f;
#pragma unroll
        for (int sl = 0; sl < 8; ++sl) o += Opart[(size_t)(bh * 8 + sl) * 2048 + idx];
        out[(size_t)(b * 4096 + qq) * 768 + h * 64 + d] = o / Ls[qq];
    }
}

// ---------------------------------------------------------------------------
extern "C" void kernel_launch(void* const* d_in, const int* in_sizes, int n_in,
                              void* d_out, int out_size, void* d_ws, size_t ws_size,
                              hipStream_t stream) {
    const float* hs = (const float*)d_in[0];
    float* outp = (float*)d_out;

    char* p = (char*)d_ws;
    const size_t SLAB = (size_t)2 * 12 * 4096 * 64 * sizeof(f16);   // 12,582,912 B
    f16* qb   = (f16*)(p + 0 * SLAB);
    f16* kb   = (f16*)(p + 1 * SLAB);
    f16* vtb  = (f16*)(p + 2 * SLAB);   // [bh][d][s]
    f16* kgb  = (f16*)(p + 3 * SLAB);
    f16* vgtb = (f16*)(p + 4 * SLAB);   // [bh][d][s]
    f16* qgb  = (f16*)(p + 5 * SLAB);
    char* p2  = p + 5 * SLAB + 196608;
    f16* xh   = (f16*)p2;
    f16* wt   = (f16*)(p2 + SLAB);
    char* p3  = p2 + SLAB + 7077888;
    float* Opart = (float*)p3;
    float* Lpart = (float*)(p3 + 1572864);

    prep<<<7008, 256, 0, stream>>>(
        hs,
        (const float*)d_in[1], (const float*)d_in[3], (const float*)d_in[5],
        (const float*)d_in[7], (const float*)d_in[9], (const float*)d_in[11],
        xh, wt);
    qkv_mfma9<<<dim3(64, 36), 256, 0, stream>>>(
        xh, wt,
        (const float*)d_in[2], (const float*)d_in[4], (const float*)d_in[6],
        (const float*)d_in[8], (const float*)d_in[10], (const float*)d_in[12],
        qb, kb, vtb, qgb, kgb, vgtb);
    band_mfma5<<<768, 256, 0, stream>>>(qb, kb, vtb, outp);
    global_part<<<192, 256, 0, stream>>>(qgb, kgb, vgtb, Opart, Lpart);
    global_reduce<<<24, 256, 0, stream>>>(Opart, Lpart, outp);
}